// Round 5
// baseline (208.625 us; speedup 1.0000x reference)
//
#include <hip/hip_runtime.h>
#include <hip/hip_bf16.h>
#include <math.h>

#define B_ 4
#define S_ 2048
#define E_ 1024
#define H_ 64
#define TPS 4           // 64-key tiles per split
#define SENT (-1.25e8f) // masked-logit sentinel (= -1e9 * 0.125)
#define NBLK 256        // persistent grid: one block per CU

typedef short bf16x8 __attribute__((ext_vector_type(8)));
typedef float f32x4 __attribute__((ext_vector_type(4)));
typedef unsigned short U16;
typedef U16 u16x8 __attribute__((ext_vector_type(8)));
typedef U16 u16x4 __attribute__((ext_vector_type(4)));

__device__ __forceinline__ U16 f2bf(float f){
    unsigned u = __builtin_bit_cast(unsigned, f);
    u += 0x7fffu + ((u >> 16) & 1u);          // RNE
    return (U16)(u >> 16);
}
__device__ __forceinline__ float bf2f(U16 h){
    return __builtin_bit_cast(float, ((unsigned)h) << 16);
}
#define MFMA16(a,b,c) __builtin_amdgcn_mfma_f32_16x16x32_bf16((a),(b),(c),0,0,0)

typedef const __attribute__((address_space(1))) void GvPtr;
typedef __attribute__((address_space(3))) void LdsPtr;
__device__ __forceinline__ void gload_lds16(const void* g, void* l){
    __builtin_amdgcn_global_load_lds((GvPtr*)g, (LdsPtr*)l, 16, 0, 0);
}

// device-scope grid barrier; cnt zeroed by hipMemsetAsync before launch
__device__ __forceinline__ void grid_barrier(unsigned* cnt){
    __syncthreads();
    if (threadIdx.x == 0){
        __threadfence();                       // release our writes device-wide
        atomicAdd(cnt, 1u);                    // device-scope RMW
        while (__hip_atomic_load(cnt, __ATOMIC_ACQUIRE, __HIP_MEMORY_SCOPE_AGENT) < NBLK)
            __builtin_amdgcn_s_sleep(2);
        __threadfence();                       // acquire: invalidate L1 + XCD L2
    }
    __syncthreads();
}

// ---------------------------------------------------------------------------
// Kernel 0: split W (3 comps, fp32) into hi/lo bf16 pair arrays (runs once,
// ~2 us; keeps the fused kernel's phase-1 free of per-block W reconversion).
// ---------------------------------------------------------------------------
__global__ __launch_bounds__(256) void prep_w(
    const float* __restrict__ Wq, const float* __restrict__ Wk,
    const float* __restrict__ Wv, U16* __restrict__ Whi, U16* __restrict__ Wlo)
{
    int i4 = (blockIdx.x*256 + threadIdx.x) * 4;     // < 3*65536
    int c = i4 >> 16, rem = i4 & 65535;
    const float* src = (c==0) ? Wq : (c==1) ? Wk : Wv;
    float4 v = *(const float4*)(src + rem);
    float a[4] = {v.x, v.y, v.z, v.w};
    u16x4 hv, lv;
    #pragma unroll
    for (int j=0;j<4;j++){ U16 h = f2bf(a[j]); hv[j]=h; lv[j]=f2bf(a[j]-bf2f(h)); }
    *(u16x4*)(Whi + i4) = hv;
    *(u16x4*)(Wlo + i4) = lv;
}

// ---------------------------------------------------------------------------
// Fused persistent kernel: 256 blocks x 512 threads, grid barriers between
// phases. Phase 1 QKV (no-LDS main loop, LDS k-reduce epilogue); phase 2
// flash attention (288 work items, 128 q-rows x 8 waves each, split-K);
// phase 3 split-K combine (+ meanV for fully-masked rows, precomputed by
// blocks 224..255 at phase-2 start).
// ---------------------------------------------------------------------------
__global__ __launch_bounds__(512, 2) void fused_kernel(
    const float* __restrict__ x, const int* __restrict__ pad,
    const U16* __restrict__ Whi_g, const U16* __restrict__ Wlo_g,
    U16* __restrict__ Qhi, U16* __restrict__ Qlo,
    U16* __restrict__ Khi, U16* __restrict__ Klo, U16* __restrict__ Vt,
    float* __restrict__ Opart, float* __restrict__ mpart, float* __restrict__ lpart,
    float* __restrict__ meanV, unsigned* __restrict__ cnt,
    float* __restrict__ out)
{
    __shared__ __align__(16) char smem[73728];   // 72 KB union (phase1 Red / phase2 tiles)
    const int tid = threadIdx.x, lane = tid & 63, wv = tid >> 6;
    const int l15 = lane & 15, quad = lane >> 4;

    //================ phase 1: QKV projection ================
    {
        float* Red = (float*)smem;
        const int m0 = blockIdx.x * 32;          // 32 rows per block
        const int bb = m0 >> 11;                 // batch (blocks never straddle)
        const int kq = wv & 3, mh = wv >> 2;     // wave = (k-quarter, m-half)

        f32x4 acc[12];                           // [comp*4 + nt]
        #pragma unroll
        for (int i=0;i<12;i++) acc[i] = f32x4{0.f,0.f,0.f,0.f};

        const float* xb = x + (size_t)(m0 + mh*16 + l15)*E_ + kq*256 + quad*8;
        const size_t wbase = (size_t)l15*E_ + kq*256 + quad*8;

        float4 xc0 = ((const float4*)xb)[0], xc1 = ((const float4*)xb)[1];
        #pragma unroll 1
        for (int s=0; s<8; ++s){
            bf16x8 ah, al;
            {
                float v[8] = {xc0.x,xc0.y,xc0.z,xc0.w,xc1.x,xc1.y,xc1.z,xc1.w};
                #pragma unroll
                for (int j2=0;j2<8;j2++){
                    U16 h = f2bf(v[j2]);
                    ah[j2] = (short)h;
                    al[j2] = (short)f2bf(v[j2] - bf2f(h));
                }
            }
            if (s < 7){
                const float* xs = xb + (s+1)*32;
                xc0 = ((const float4*)xs)[0];
                xc1 = ((const float4*)xs)[1];
            }
            #pragma unroll
            for (int c=0;c<3;++c)
            #pragma unroll
            for (int nt=0;nt<4;++nt){
                const size_t o2 = (size_t)c*65536 + wbase + (size_t)nt*16*E_ + s*32;
                bf16x8 bh = *(const bf16x8*)(Whi_g + o2);
                bf16x8 bl = *(const bf16x8*)(Wlo_g + o2);
                acc[c*4+nt] = MFMA16(ah, bh, acc[c*4+nt]);   // hi*hi
                acc[c*4+nt] = MFMA16(ah, bl, acc[c*4+nt]);   // hi*lo
                acc[c*4+nt] = MFMA16(al, bh, acc[c*4+nt]);   // lo*hi
            }
        }
        // cross-k-quarter reduce via LDS
        if (kq != 0){
            float* rp = Red + (size_t)((kq-1)*2 + mh)*12*64*4;
            #pragma unroll
            for (int a=0;a<12;++a) *(f32x4*)(rp + (a*64 + lane)*4) = acc[a];
        }
        __syncthreads();
        if (kq == 0){
            #pragma unroll
            for (int k2=0;k2<3;++k2){
                const float* rp = Red + (size_t)(k2*2 + mh)*12*64*4;
                #pragma unroll
                for (int a=0;a<12;++a) acc[a] += *(const f32x4*)(rp + (a*64 + lane)*4);
            }
            #pragma unroll
            for (int nt=0;nt<4;++nt){
                const int h = nt*16 + l15;
                const int row = m0 + mh*16 + quad*4;
                #pragma unroll
                for (int r=0;r<4;++r){
                    float vq = acc[nt][r];   U16 hq = f2bf(vq);
                    Qhi[(size_t)(row+r)*H_ + h] = hq;
                    Qlo[(size_t)(row+r)*H_ + h] = f2bf(vq - bf2f(hq));
                    float vk = acc[4+nt][r]; U16 hk = f2bf(vk);
                    Khi[(size_t)(row+r)*H_ + h] = hk;
                    Klo[(size_t)(row+r)*H_ + h] = f2bf(vk - bf2f(hk));
                }
                u16x4 pk;
                #pragma unroll
                for (int r=0;r<4;++r) pk[r] = f2bf(acc[8+nt][r]);
                *(u16x4*)(Vt + ((size_t)bb*H_ + h)*S_ + (row & (S_-1))) = pk;  // V^T
            }
        }
    }
    grid_barrier(cnt + 0);

    //================ phase 2: flash attention (split-K) ================
    {
        U16* KtH = (U16*)smem;
        U16* KtL = KtH + 4096;
        U16* Vts = KtL + 4096;
        U16* Ps  = Vts + 4096;       // 8 waves x 16x80

        // meanV (sum of V columns) by the 32 lightest-loaded blocks
        if (blockIdx.x >= 224){
            const int idx = (blockIdx.x - 224)*8 + wv;   // = b*64 + h
            const U16* vp = Vt + (size_t)idx*S_;
            float sm = 0.f;
            #pragma unroll
            for (int it2=0; it2<4; ++it2){
                u16x8 d = *(const u16x8*)(vp + (it2*64 + lane)*8);
                #pragma unroll
                for (int j2=0;j2<8;j2++) sm += bf2f(d[j2]);
            }
            #pragma unroll
            for (int m2=1; m2<=32; m2<<=1) sm += __shfl_xor(sm, m2);
            if (lane == 0) meanV[idx] = sm;
        }

        const int srow = tid >> 3, sg = tid & 7, sgs = sg ^ (srow & 7);
        const int sb16 = wv*512;            // wave-uniform LDS base (u16 units)
        const int sw = l15 & 7;

        for (int rd=0; rd<2; ++rd){
            const int n = blockIdx.x + rd*NBLK;
            if (n >= 288) continue;          // block-uniform
            const int b = n & 3;
            int j = n >> 2, q = 15;          // heavy-first decode: q128 desc
            for (;;){ const int c = (q>>1)+1; if (j < c) break; j -= c; --q; }
            const int sp = j;
            const int t0 = sp*TPS, t1 = min(t0+TPS, 2*q+2);

            const size_t qrow = (size_t)b*S_ + q*128 + wv*16 + l15;
            bf16x8 aqh0 = *(const bf16x8*)(Qhi + qrow*H_ + quad*8);
            bf16x8 aqh1 = *(const bf16x8*)(Qhi + qrow*H_ + 32 + quad*8);
            bf16x8 aql0 = *(const bf16x8*)(Qlo + qrow*H_ + quad*8);
            bf16x8 aql1 = *(const bf16x8*)(Qlo + qrow*H_ + 32 + quad*8);

            float m_i = -INFINITY, l_i = 0.f;
            f32x4 o[4];
            #pragma unroll
            for (int i=0;i<4;i++) o[i] = f32x4{0.f,0.f,0.f,0.f};
            const int qg = q*128 + wv*16 + l15;
            const int qmax = q*128 + wv*16 + 15;
            U16* Pw = Ps + wv*1280;

            for (int t=t0; t<t1; ++t){
                const int kb = t*64;
                __syncthreads();             // prev LDS reads done
                gload_lds16(Khi + ((size_t)b*S_ + kb + srow)*H_ + sgs*8, KtH + sb16);
                gload_lds16(Klo + ((size_t)b*S_ + kb + srow)*H_ + sgs*8, KtL + sb16);
                gload_lds16(Vt + ((size_t)b*H_ + srow)*S_ + kb + sgs*8, Vts + sb16);
                const unsigned long long pm = __ballot(pad[(size_t)b*S_ + kb + lane] != 0);
                __syncthreads();             // vmcnt drained -> staging landed

                if (kb <= qmax){             // wave-level causal skip (no barriers inside)
                    f32x4 z[4];
                    #pragma unroll
                    for (int nt=0; nt<4; nt++){
                        const int kr = (nt*16 + l15)*8;
                        bf16x8 kh0 = ((const bf16x8*)KtH)[kr + (quad ^ sw)];
                        bf16x8 kh1 = ((const bf16x8*)KtH)[kr + ((4+quad) ^ sw)];
                        bf16x8 kl0 = ((const bf16x8*)KtL)[kr + (quad ^ sw)];
                        bf16x8 kl1 = ((const bf16x8*)KtL)[kr + ((4+quad) ^ sw)];
                        f32x4 zz = f32x4{0.f,0.f,0.f,0.f};
                        zz = MFMA16(kh0, aqh0, zz);
                        zz = MFMA16(kh1, aqh1, zz);
                        zz = MFMA16(kh0, aql0, zz);
                        zz = MFMA16(kh1, aql1, zz);
                        zz = MFMA16(kl0, aqh0, zz);
                        zz = MFMA16(kl1, aqh1, zz);
                        z[nt] = zz;
                    }
                    float rmax = -INFINITY;
                    #pragma unroll
                    for (int nt=0; nt<4; nt++){
                        const int rel = qg - kb - nt*16 - quad*4;
                        const unsigned mb = (unsigned)(pm >> (nt*16 + quad*4)) & 0xFu;
                        #pragma unroll
                        for (int r=0;r<4;r++){
                            const bool ok = (r <= rel) && ((mb >> r) & 1u);
                            const float v = ok ? z[nt][r]*0.125f : SENT;
                            z[nt][r] = v;
                            rmax = fmaxf(rmax, v);
                        }
                    }
                    rmax = fmaxf(rmax, __shfl_xor(rmax, 16));
                    rmax = fmaxf(rmax, __shfl_xor(rmax, 32));
                    const float mn = fmaxf(m_i, rmax);
                    const float alpha = __expf(m_i - mn);
                    m_i = mn;
                    float rsum = 0.f;
                    #pragma unroll
                    for (int nt=0; nt<4; nt++)
                    #pragma unroll
                    for (int r=0;r<4;r++){
                        const float pe = __expf(z[nt][r] - mn);
                        z[nt][r] = pe;
                        rsum += pe;
                    }
                    rsum += __shfl_xor(rsum, 16);
                    rsum += __shfl_xor(rsum, 32);
                    l_i = l_i*alpha + rsum;
                    #pragma unroll
                    for (int nt=0; nt<4; nt++)
                    #pragma unroll
                    for (int r=0;r<4;r++) o[nt][r] *= alpha;

                    #pragma unroll
                    for (int nt=0; nt<4; nt++){
                        u16x4 pk;
                        #pragma unroll
                        for (int r=0;r<4;r++) pk[r] = f2bf(z[nt][r]);
                        *(u16x4*)(Pw + l15*80 + nt*16 + quad*4) = pk;
                    }
                    #pragma unroll
                    for (int ks=0; ks<2; ks++){
                        bf16x8 bp = *(const bf16x8*)(Pw + l15*80 + ks*32 + quad*8);
                        #pragma unroll
                        for (int nt=0; nt<4; nt++){
                            bf16x8 av2 = ((const bf16x8*)Vts)[(nt*16 + l15)*8 + ((ks*4+quad) ^ sw)];
                            o[nt] = MFMA16(av2, bp, o[nt]);
                        }
                    }
                }
            }
            const size_t rbase = ((size_t)((b*16 + q)*8 + sp))*128 + wv*16 + l15;
            if (quad == 0){ mpart[rbase] = m_i; lpart[rbase] = l_i; }
            #pragma unroll
            for (int nt=0; nt<4; nt++)
                *(f32x4*)(Opart + rbase*64 + nt*16 + quad*4) = o[nt];
        }
    }
    grid_barrier(cnt + 1);

    //================ phase 3: combine split-K partials ================
    {
        const int base = (blockIdx.x*512 + tid)*4;   // 4 consecutive h
        const int h0 = base & 63;
        const int qq = (base >> 6) & (S_-1);
        const int b3 = base >> 17;
        const int q128 = qq >> 7, r = qq & 127;
        const int ns = (q128 >> 1) + 1;
        const size_t rb = ((size_t)(b3*16 + q128)*8)*128 + r;
        float M = -INFINITY;
        for (int s2=0; s2<ns; ++s2) M = fmaxf(M, mpart[rb + (size_t)s2*128]);
        f32x4 res;
        if (M == SENT){                      // fully masked: uniform over all S keys
            #pragma unroll
            for (int j2=0;j2<4;j2++) res[j2] = meanV[b3*64 + h0 + j2] * (1.f/(float)S_);
        } else {
            float L = 0.f;
            f32x4 av = f32x4{0.f,0.f,0.f,0.f};
            for (int s2=0; s2<ns; ++s2){
                const float mi = mpart[rb + (size_t)s2*128];
                const float w = __expf(mi - M);   // 0 for dead/causal-skipped splits
                L += w * lpart[rb + (size_t)s2*128];
                const f32x4 op = *(const f32x4*)(Opart + (rb + (size_t)s2*128)*64 + h0);
                av += op * w;
            }
            res = av * (1.f / L);
        }
        *(f32x4*)(out + base) = res;
    }
}

// ---------------------------------------------------------------------------
// Workspace: Whi 0 (384K) | Wlo 384K | Qhi 1M | Qlo 2M | Khi 3M | Klo 4M |
//   Vt 4M+... wait: Vt 5M? -> Qhi@1M Qlo@2M Khi@3M Klo@4M Vt@5M? Use:
//   Whi@0 Wlo@0.5M Qhi@1M Qlo@2M Khi@3M Klo@4M Vt@5M (1M) | Opart@6M (16M) |
//   mpart@22M (256K) | lpart@22.25M (256K) | meanV@22.5M (1K) | cnt@22.51M
// ---------------------------------------------------------------------------
extern "C" void kernel_launch(void* const* d_in, const int* in_sizes, int n_in,
                              void* d_out, int out_size, void* d_ws, size_t ws_size,
                              hipStream_t stream)
{
    (void)in_sizes; (void)n_in; (void)out_size; (void)ws_size;
    const float* x  = (const float*)d_in[0];
    const int* pad  = (const int*)d_in[1];
    const float* Wq = (const float*)d_in[2];
    const float* Wk = (const float*)d_in[3];
    const float* Wv = (const float*)d_in[4];
    float* out = (float*)d_out;
    char* ws = (char*)d_ws;
    const size_t MB = 1u << 20;
    U16* Whi = (U16*)(ws);
    U16* Wlo = (U16*)(ws + MB/2);
    U16* Qhi = (U16*)(ws + 1*MB);
    U16* Qlo = (U16*)(ws + 2*MB);
    U16* Khi = (U16*)(ws + 3*MB);
    U16* Klo = (U16*)(ws + 4*MB);
    U16* Vt  = (U16*)(ws + 5*MB);
    float* Opart = (float*)(ws + 6*MB);
    float* mpart = (float*)(ws + 22*MB);
    float* lpart = (float*)(ws + 22*MB + (1u<<18));
    float* meanV = (float*)(ws + 22*MB + 2*(1u<<18));
    unsigned* cnt = (unsigned*)(ws + 22*MB + 2*(1u<<18) + 4096);

    hipMemsetAsync(cnt, 0, 64, stream);   // zero grid-barrier counters (capture-safe)
    prep_w<<<dim3(192), 256, 0, stream>>>(Wq, Wk, Wv, Whi, Wlo);
    fused_kernel<<<dim3(NBLK), 512, 0, stream>>>(x, pad, Whi, Wlo,
                                                 Qhi, Qlo, Khi, Klo, Vt,
                                                 Opart, mpart, lpart, meanV, cnt, out);
}

// Round 6
// 151.296 us; speedup vs baseline: 1.3789x; 1.3789x over previous
//
#include <hip/hip_runtime.h>
#include <hip/hip_bf16.h>
#include <math.h>

#define B_ 4
#define S_ 2048
#define E_ 1024
#define H_ 64
#define NQT 32          // S/64 q-tiles
#define SPLITS 8
#define TPS 4           // 64-key tiles per split (256 keys/split)
#define SENT (-1.25e8f) // masked-logit sentinel (= -1e9 * 0.125)

typedef short bf16x8 __attribute__((ext_vector_type(8)));
typedef float f32x4 __attribute__((ext_vector_type(4)));
typedef unsigned short U16;
typedef U16 u16x8 __attribute__((ext_vector_type(8)));
typedef U16 u16x4 __attribute__((ext_vector_type(4)));

__device__ __forceinline__ U16 f2bf(float f){
    unsigned u = __builtin_bit_cast(unsigned, f);
    u += 0x7fffu + ((u >> 16) & 1u);          // RNE
    return (U16)(u >> 16);
}
__device__ __forceinline__ float bf2f(U16 h){
    return __builtin_bit_cast(float, ((unsigned)h) << 16);
}
#define MFMA16(a,b,c) __builtin_amdgcn_mfma_f32_16x16x32_bf16((a),(b),(c),0,0,0)

// ---------------------------------------------------------------------------
// Kernel 0: split W (3 comps, fp32) into hi/lo bf16 pair arrays.
// ---------------------------------------------------------------------------
__global__ __launch_bounds__(256) void prep_w(
    const float* __restrict__ Wq, const float* __restrict__ Wk,
    const float* __restrict__ Wv, U16* __restrict__ Whi, U16* __restrict__ Wlo)
{
    int i4 = (blockIdx.x*256 + threadIdx.x) * 4;     // < 3*65536
    int c = i4 >> 16, rem = i4 & 65535;
    const float* src = (c==0) ? Wq : (c==1) ? Wk : Wv;
    float4 v = *(const float4*)(src + rem);
    float a[4] = {v.x, v.y, v.z, v.w};
    u16x4 hv, lv;
    #pragma unroll
    for (int j=0;j<4;j++){ U16 h = f2bf(a[j]); hv[j]=h; lv[j]=f2bf(a[j]-bf2f(h)); }
    *(u16x4*)(Whi + i4) = hv;
    *(u16x4*)(Wlo + i4) = lv;
}

// ---------------------------------------------------------------------------
// Kernel 1: QKV projection. Grid 512 x 512 thr: block = 16 m-rows, wave =
// one of 8 k-slices (128 k, 4 steps of 32). NO barriers in main loop; each
// wave streams x (HBM, prefetched) + W frags (L2) into 36 MFMAs/step.
// log2 LDS reduce epilogue (peak 48 KB). 2 blocks/CU = 4 waves/SIMD.
// ---------------------------------------------------------------------------
__global__ __launch_bounds__(512, 4) void qkv_kernel(
    const float* __restrict__ x, const U16* __restrict__ Whi_g,
    const U16* __restrict__ Wlo_g,
    U16* __restrict__ Qhi, U16* __restrict__ Qlo,
    U16* __restrict__ Khi, U16* __restrict__ Klo, U16* __restrict__ Vt)
{
    __shared__ __align__(16) float Red[4][12*64*4];   // 4 sets x 12 KB = 48 KB
    const int m0 = blockIdx.x * 16;
    const int bb = m0 >> 11;
    const int tid = threadIdx.x, lane = tid & 63, kq = tid >> 6;
    const int l15 = lane & 15, quad = lane >> 4;

    f32x4 acc[12];                            // [comp*4 + nt]
    #pragma unroll
    for (int i=0;i<12;i++) acc[i] = f32x4{0.f,0.f,0.f,0.f};

    const float* xb = x + (size_t)(m0 + l15)*E_ + kq*128 + quad*8;
    const size_t wbase = (size_t)l15*E_ + kq*128 + quad*8;

    float4 xc0 = ((const float4*)xb)[0], xc1 = ((const float4*)xb)[1];
    #pragma unroll 1
    for (int s=0; s<4; ++s){
        bf16x8 ah, al;
        {
            float v[8] = {xc0.x,xc0.y,xc0.z,xc0.w,xc1.x,xc1.y,xc1.z,xc1.w};
            #pragma unroll
            for (int j=0;j<8;j++){
                U16 h = f2bf(v[j]);
                ah[j] = (short)h;
                al[j] = (short)f2bf(v[j] - bf2f(h));
            }
        }
        if (s < 3){
            const float* xs = xb + (s+1)*32;
            xc0 = ((const float4*)xs)[0];
            xc1 = ((const float4*)xs)[1];
        }
        #pragma unroll
        for (int c=0;c<3;++c)
        #pragma unroll
        for (int nt=0;nt<4;++nt){
            const size_t o2 = (size_t)c*65536 + wbase + (size_t)nt*16*E_ + s*32;
            bf16x8 bh = *(const bf16x8*)(Whi_g + o2);
            bf16x8 bl = *(const bf16x8*)(Wlo_g + o2);
            acc[c*4+nt] = MFMA16(ah, bh, acc[c*4+nt]);   // hi*hi
            acc[c*4+nt] = MFMA16(ah, bl, acc[c*4+nt]);   // hi*lo
            acc[c*4+nt] = MFMA16(al, bh, acc[c*4+nt]);   // lo*hi
        }
    }

    // log2 cross-wave reduce: 8 -> 4 -> 2 -> 1
    if (kq >= 4){
        float* w = &Red[kq-4][0];
        #pragma unroll
        for (int a=0;a<12;++a) *(f32x4*)(w + (a*64+lane)*4) = acc[a];
    }
    __syncthreads();
    if (kq < 4){
        const float* rdp = &Red[kq][0];
        #pragma unroll
        for (int a=0;a<12;++a) acc[a] += *(const f32x4*)(rdp + (a*64+lane)*4);
    }
    __syncthreads();
    if (kq == 2 || kq == 3){
        float* w = &Red[kq-2][0];
        #pragma unroll
        for (int a=0;a<12;++a) *(f32x4*)(w + (a*64+lane)*4) = acc[a];
    }
    __syncthreads();
    if (kq < 2){
        const float* rdp = &Red[kq][0];
        #pragma unroll
        for (int a=0;a<12;++a) acc[a] += *(const f32x4*)(rdp + (a*64+lane)*4);
    }
    __syncthreads();
    if (kq == 1){
        float* w = &Red[0][0];
        #pragma unroll
        for (int a=0;a<12;++a) *(f32x4*)(w + (a*64+lane)*4) = acc[a];
    }
    __syncthreads();
    if (kq == 0){
        const float* rdp = &Red[0][0];
        #pragma unroll
        for (int a=0;a<12;++a) acc[a] += *(const f32x4*)(rdp + (a*64+lane)*4);

        #pragma unroll
        for (int nt=0;nt<4;++nt){
            const int h = nt*16 + l15;
            const int row = m0 + quad*4;
            #pragma unroll
            for (int r=0;r<4;++r){
                float vq = acc[nt][r];   U16 hq = f2bf(vq);
                Qhi[(size_t)(row+r)*H_ + h] = hq;
                Qlo[(size_t)(row+r)*H_ + h] = f2bf(vq - bf2f(hq));
                float vk = acc[4+nt][r]; U16 hk = f2bf(vk);
                Khi[(size_t)(row+r)*H_ + h] = hk;
                Klo[(size_t)(row+r)*H_ + h] = f2bf(vk - bf2f(hk));
            }
            u16x4 pk;
            #pragma unroll
            for (int r=0;r<4;++r) pk[r] = f2bf(acc[8+nt][r]);
            *(u16x4*)(Vt + ((size_t)bb*H_ + h)*S_ + (row & (S_-1))) = pk;  // V^T
        }
    }
}

// ---------------------------------------------------------------------------
// Kernel 2: per-(b,h) sum of V (for reference's uniform-softmax fully-masked
// rows). 256 blocks x 256 thr, vectorized.
// ---------------------------------------------------------------------------
__global__ __launch_bounds__(256) void meanv_kernel(const U16* __restrict__ Vt,
                                                    float* __restrict__ meanV)
{
    const int idx = blockIdx.x;                 // = b*64 + h
    const U16* src = Vt + (size_t)idx*S_;
    u16x8 d = *(const u16x8*)(src + threadIdx.x*8);
    float sum = 0.f;
    #pragma unroll
    for (int j=0;j<8;j++) sum += bf2f(d[j]);
    #pragma unroll
    for (int m=1; m<=32; m<<=1) sum += __shfl_xor(sum, m);
    __shared__ float red[4];
    if ((threadIdx.x & 63) == 0) red[threadIdx.x >> 6] = sum;
    __syncthreads();
    if (threadIdx.x == 0) meanV[idx] = red[0]+red[1]+red[2]+red[3];   // raw sum
}

// ---------------------------------------------------------------------------
// Kernel 3: flash attention, split-K, S^T form. Single 34 KB LDS buffer
// (4 blocks/CU) with REGISTER-staged prefetch: tile t+1's global loads issue
// before compute(t), ds_write after the post-compute barrier.
// ---------------------------------------------------------------------------
__global__ __launch_bounds__(256, 4) void attn_kernel(
    const U16* __restrict__ Qhi, const U16* __restrict__ Qlo,
    const U16* __restrict__ Khi, const U16* __restrict__ Klo,
    const U16* __restrict__ Vt, const int* __restrict__ pad,
    float* __restrict__ Opart, float* __restrict__ mpart, float* __restrict__ lpart)
{
    const int qt = blockIdx.x, b = blockIdx.y, sp = blockIdx.z;
    const int t0 = sp * TPS;
    if (t0 > qt) return;
    const int t1 = min(t0 + TPS, qt + 1);

    __shared__ __align__(16) U16 KtH[64*64], KtL[64*64], Vts[64*64];
    __shared__ __align__(16) U16 Ps[4][16*80];   // per-wave P[q=16][key 64], stride 80

    const int tid = threadIdx.x, lane = tid & 63, wv = tid >> 6;
    const int l15 = lane & 15, quad = lane >> 4;
    const int sw = l15 & 7;

    // this thread's two staging slots (same for every tile)
    int srow[2], sg[2];
    #pragma unroll
    for (int ch=0; ch<2; ++ch){
        const int u = wv*128 + ch*64 + lane;
        srow[ch] = u >> 3;
        sg[ch]   = u & 7;
    }

    u16x8 skh[2], skl[2], svv[2];
    auto load_regs = [&](int t){
        const int kb2 = t * 64;
        #pragma unroll
        for (int ch=0; ch<2; ++ch){
            const size_t kro = ((size_t)b*S_ + kb2 + srow[ch])*H_ + sg[ch]*8;
            skh[ch] = *(const u16x8*)(Khi + kro);
            skl[ch] = *(const u16x8*)(Klo + kro);
            svv[ch] = *(const u16x8*)(Vt + ((size_t)b*H_ + srow[ch])*S_ + kb2 + sg[ch]*8);
        }
    };
    auto write_lds = [&](){
        #pragma unroll
        for (int ch=0; ch<2; ++ch){
            const int di = srow[ch]*8 + (sg[ch] ^ (srow[ch] & 7));   // XOR-swizzled dest
            ((u16x8*)KtH)[di] = skh[ch];
            ((u16x8*)KtL)[di] = skl[ch];
            ((u16x8*)Vts)[di] = svv[ch];
        }
    };

    // Q fragments as B-operand (lane l15 = q-row, k = d = quad*8+j)
    const size_t qrow = (size_t)b*S_ + qt*64 + wv*16 + l15;
    bf16x8 aqh0 = *(const bf16x8*)(Qhi + qrow*H_ + quad*8);
    bf16x8 aqh1 = *(const bf16x8*)(Qhi + qrow*H_ + 32 + quad*8);
    bf16x8 aql0 = *(const bf16x8*)(Qlo + qrow*H_ + quad*8);
    bf16x8 aql1 = *(const bf16x8*)(Qlo + qrow*H_ + 32 + quad*8);

    float m_i = -INFINITY, l_i = 0.f;
    f32x4 o[4];
    #pragma unroll
    for (int i=0;i<4;i++) o[i] = f32x4{0.f,0.f,0.f,0.f};
    const int qg = qt*64 + wv*16 + l15;
    U16* Pw = &Ps[wv][0];

    load_regs(t0);
    int pv = pad[(size_t)b*S_ + t0*64 + lane];
    write_lds();
    __syncthreads();

    for (int t = t0; t < t1; ++t) {
        const int kb = t * 64;
        int pvn = 0;
        if (t + 1 < t1){
            load_regs(t+1);                     // in flight during compute below
            pvn = pad[(size_t)b*S_ + (t+1)*64 + lane];
        }
        const unsigned long long pm = __ballot(pv != 0);

        // --- S^T = K Q^T (hi/lo, fp32-accurate logits) ---
        f32x4 z[4];
        #pragma unroll
        for (int nt=0; nt<4; nt++){
            const int kr = (nt*16 + l15)*8;
            bf16x8 kh0 = ((const bf16x8*)KtH)[kr + (quad ^ sw)];
            bf16x8 kh1 = ((const bf16x8*)KtH)[kr + ((4+quad) ^ sw)];
            bf16x8 kl0 = ((const bf16x8*)KtL)[kr + (quad ^ sw)];
            bf16x8 kl1 = ((const bf16x8*)KtL)[kr + ((4+quad) ^ sw)];
            f32x4 zz = f32x4{0.f,0.f,0.f,0.f};
            zz = MFMA16(kh0, aqh0, zz);
            zz = MFMA16(kh1, aqh1, zz);
            zz = MFMA16(kh0, aql0, zz);
            zz = MFMA16(kh1, aql1, zz);
            zz = MFMA16(kl0, aqh0, zz);
            zz = MFMA16(kl1, aqh1, zz);
            z[nt] = zz;
        }
        // --- mask + scale ---
        float rmax = -INFINITY;
        #pragma unroll
        for (int nt=0; nt<4; nt++){
            const int rel = qg - kb - nt*16 - quad*4;
            const unsigned mb = (unsigned)(pm >> (nt*16 + quad*4)) & 0xFu;
            #pragma unroll
            for (int r=0;r<4;r++){
                const bool ok = (r <= rel) && ((mb >> r) & 1u);
                const float v = ok ? z[nt][r]*0.125f : SENT;
                z[nt][r] = v;
                rmax = fmaxf(rmax, v);
            }
        }
        rmax = fmaxf(rmax, __shfl_xor(rmax, 16));
        rmax = fmaxf(rmax, __shfl_xor(rmax, 32));
        const float mn = fmaxf(m_i, rmax);
        const float alpha = __expf(m_i - mn);
        m_i = mn;
        float rsum = 0.f;
        #pragma unroll
        for (int nt=0; nt<4; nt++)
        #pragma unroll
        for (int r=0;r<4;r++){
            const float pe = __expf(z[nt][r] - mn);
            z[nt][r] = pe;
            rsum += pe;
        }
        rsum += __shfl_xor(rsum, 16);
        rsum += __shfl_xor(rsum, 32);
        l_i = l_i*alpha + rsum;
        #pragma unroll
        for (int nt=0; nt<4; nt++)
        #pragma unroll
        for (int r=0;r<4;r++) o[nt][r] *= alpha;

        // --- P -> per-wave LDS row-major [q=l15][key] ---
        #pragma unroll
        for (int nt=0; nt<4; nt++){
            u16x4 pk;
            #pragma unroll
            for (int r=0;r<4;r++) pk[r] = f2bf(z[nt][r]);
            *(u16x4*)(Pw + l15*80 + nt*16 + quad*4) = pk;
        }
        // --- O^T += V^T P^T ---
        #pragma unroll
        for (int ks=0; ks<2; ks++){
            bf16x8 bp = *(const bf16x8*)(Pw + l15*80 + ks*32 + quad*8);
            #pragma unroll
            for (int nt=0; nt<4; nt++){
                bf16x8 av = ((const bf16x8*)Vts)[(nt*16 + l15)*8 + ((ks*4+quad) ^ sw)];
                o[nt] = MFMA16(av, bp, o[nt]);
            }
        }

        if (t + 1 < t1){
            __syncthreads();          // all waves done reading tile t
            write_lds();              // stage tile t+1 (regs already loaded)
            __syncthreads();          // tile t+1 visible
        }
        pv = pvn;
    }
    // partials: row = [b][qt][sp][q 64], cols h
    const size_t rbase = ((size_t)((b*NQT + qt)*SPLITS + sp))*64 + wv*16 + l15;
    if (quad == 0) { mpart[rbase] = m_i; lpart[rbase] = l_i; }
    #pragma unroll
    for (int nt=0; nt<4; nt++)
        *((f32x4*)(Opart + rbase*H_ + nt*16 + quad*4)) = o[nt];
}

// ---------------------------------------------------------------------------
// Kernel 4: merge split-K partials; meanV path for fully-masked rows.
// One thread per 4 h (f32x4). 512 blocks x 256 thr.
// ---------------------------------------------------------------------------
__global__ __launch_bounds__(256) void combine_kernel(
    const float* __restrict__ Opart, const float* __restrict__ mpart,
    const float* __restrict__ lpart, const float* __restrict__ meanV,
    float* __restrict__ out)
{
    const int base = (blockIdx.x*256 + threadIdx.x)*4;
    const int h0 = base & 63;
    const int q = (base >> 6) & (S_-1);
    const int b = base >> 17;
    const int qt = q >> 6, r = q & 63;
    const int ns = (qt >> 2) + 1;
    const size_t rb = ((size_t)(b*NQT + qt)*SPLITS)*64 + r;
    float M = -INFINITY;
    for (int s2=0; s2<ns; ++s2) M = fmaxf(M, mpart[rb + (size_t)s2*64]);
    f32x4 res;
    if (M == SENT){                      // fully masked: uniform over all S keys
        #pragma unroll
        for (int j=0;j<4;j++) res[j] = meanV[b*64 + h0 + j] * (1.f/(float)S_);
    } else {
        float L = 0.f;
        f32x4 av = f32x4{0.f,0.f,0.f,0.f};
        for (int s2=0; s2<ns; ++s2){
            const float mi = mpart[rb + (size_t)s2*64];
            const float w = __expf(mi - M);   // 0 for dead splits
            L += w * lpart[rb + (size_t)s2*64];
            const f32x4 op = *(const f32x4*)(Opart + (rb + (size_t)s2*64)*H_ + h0);
            av += op * w;
        }
        res = av * (1.f / L);
    }
    *(f32x4*)(out + base) = res;
}

// ---------------------------------------------------------------------------
// Workspace: Whi@0 (384K) | Wlo@0.5M | Qhi@1M | Qlo@2M | Khi@3M | Klo@4M |
//   Vt@5M (1M) | Opart@6M (16M) | mpart@22M (256K) | lpart@22.25M (256K) |
//   meanV@22.5M (1K)
// ---------------------------------------------------------------------------
extern "C" void kernel_launch(void* const* d_in, const int* in_sizes, int n_in,
                              void* d_out, int out_size, void* d_ws, size_t ws_size,
                              hipStream_t stream)
{
    (void)in_sizes; (void)n_in; (void)out_size; (void)ws_size;
    const float* x  = (const float*)d_in[0];
    const int* pad  = (const int*)d_in[1];
    const float* Wq = (const float*)d_in[2];
    const float* Wk = (const float*)d_in[3];
    const float* Wv = (const float*)d_in[4];
    float* out = (float*)d_out;
    char* ws = (char*)d_ws;
    const size_t MB = 1u << 20;
    U16* Whi = (U16*)(ws);
    U16* Wlo = (U16*)(ws + MB/2);
    U16* Qhi = (U16*)(ws + 1*MB);
    U16* Qlo = (U16*)(ws + 2*MB);
    U16* Khi = (U16*)(ws + 3*MB);
    U16* Klo = (U16*)(ws + 4*MB);
    U16* Vt  = (U16*)(ws + 5*MB);
    float* Opart = (float*)(ws + 6*MB);
    float* mpart = (float*)(ws + 22*MB);
    float* lpart = (float*)(ws + 22*MB + (1u<<18));
    float* meanV = (float*)(ws + 22*MB + 2*(1u<<18));

    prep_w<<<dim3(192), 256, 0, stream>>>(Wq, Wk, Wv, Whi, Wlo);
    qkv_kernel<<<dim3(512), 512, 0, stream>>>(x, Whi, Wlo, Qhi, Qlo, Khi, Klo, Vt);
    meanv_kernel<<<dim3(256), 256, 0, stream>>>(Vt, meanV);
    attn_kernel<<<dim3(NQT, B_, SPLITS), 256, 0, stream>>>(Qhi, Qlo, Khi, Klo, Vt, pad,
                                                           Opart, mpart, lpart);
    combine_kernel<<<dim3(512), 256, 0, stream>>>(Opart, mpart, lpart, meanV, out);
}